// Round 3
// baseline (553.564 us; speedup 1.0000x reference)
//
#include <hip/hip_runtime.h>
#include <math.h>

#define NN 13824   // D*H*W
#define LW 24      // line width
#define GRID 1024  // 4 blocks/CU x 256 CU -> all blocks co-resident (required for gbar)
#define NTHR 256

// ---------------- grid-wide barrier: per-block flags + block-0 scan ----------------
// Arrival = each block release-stores a generation into its OWN 128B-padded flag
// (parallel, uncontended); block 0's 256 threads scan flags (4 each); block 0
// release-stores gen; everyone polls gen. Ordering: writers syncthreads+threadfence
// -> release flag -> block0 acquire scan -> release gen -> waiters acquire fence.
__device__ __forceinline__ void gbar(unsigned* __restrict__ flags,
                                     unsigned* __restrict__ gen,
                                     unsigned target)
{
    __syncthreads();
    const int tid = threadIdx.x;
    const int bid = blockIdx.x;
    if (tid == 0) {
        __threadfence();   // make this block's writes agent-visible
        __hip_atomic_store(&flags[bid * 32], target, __ATOMIC_RELEASE, __HIP_MEMORY_SCOPE_AGENT);
    }
    if (bid == 0) {
        for (int j = tid; j < GRID; j += NTHR) {
            while (__hip_atomic_load(&flags[j * 32], __ATOMIC_RELAXED, __HIP_MEMORY_SCOPE_AGENT) < target)
                __builtin_amdgcn_s_sleep(1);
        }
        __builtin_amdgcn_fence(__ATOMIC_ACQUIRE, "agent");
        __syncthreads();   // all scanners done
        if (tid == 0)
            __hip_atomic_store(gen, target, __ATOMIC_RELEASE, __HIP_MEMORY_SCOPE_AGENT);
    }
    if (tid == 0) {
        while (__hip_atomic_load(gen, __ATOMIC_RELAXED, __HIP_MEMORY_SCOPE_AGENT) < target)
            __builtin_amdgcn_s_sleep(2);
        __builtin_amdgcn_fence(__ATOMIC_ACQUIRE, "agent");
    }
    __syncthreads();
}

// ---------------- phase: fused GN-apply + residual + projection ----------------
// 648 units (216 tiles x 3 tensors) on 1024 blocks: single round.
// smem: hs[4096] + ws[4352] = 8448 floats (33.8 KB).
__device__ void proj_phase(float* __restrict__ smem,
    const float* __restrict__ x, const float* __restrict__ cross,
    const float* __restrict__ gsum, const float* __restrict__ gn_g,
    const float* __restrict__ gn_b, float* __restrict__ h_out, int mode,
    const float* __restrict__ theta_w, const float* __restrict__ theta_b,
    const float* __restrict__ phi_w, const float* __restrict__ phi_b,
    const float* __restrict__ g_w, const float* __restrict__ g_b,
    float* __restrict__ theta, float* __restrict__ phi, float* __restrict__ gv)
{
    float* hs = smem;            // hs[c*64 + nl]
    float* ws = smem + 4096;     // scratch (cross^T) then weights^T [c*68 + d]
    const int tid = threadIdx.x;

    for (int unit = blockIdx.x; unit < 648; unit += GRID) {
        const int tile = unit / 3, ts = unit % 3;
        const int n0 = tile * 64;
        const float* wsel = (ts == 0) ? theta_w : (ts == 1) ? phi_w : g_w;
        const float* bsel = (ts == 0) ? theta_b : (ts == 1) ? phi_b : g_b;
        float*       osel = (ts == 0) ? theta   : (ts == 1) ? phi   : gv;

        if (mode == 0) {
            for (int i = tid; i < 4096; i += NTHR) {
                int c = i >> 6, nl = i & 63;
                hs[c * 64 + nl] = x[(size_t)c * NN + n0 + nl];
            }
        } else {
            for (int i = tid; i < 4096; i += NTHR) {       // cross^T into scratch
                int nl = i >> 6, c = i & 63;
                ws[c * 68 + nl] = cross[(size_t)(n0 + nl) * 64 + c];
            }
            __syncthreads();
            const float inv_cnt = 1.f / 55296.f;
            for (int i = tid; i < 4096; i += NTHR) {
                int c = i >> 6, nl = i & 63;
                int gr = c >> 2;
                float mean = gsum[gr * 16] * inv_cnt;
                float var = gsum[512 + gr * 16] * inv_cnt - mean * mean;
                float v = (ws[c * 68 + nl] - mean) * rsqrtf(var + 1e-5f) * gn_g[c] + gn_b[c];
                size_t o = (size_t)c * NN + n0 + nl;
                float hv = x[o] + v;
                hs[c * 64 + nl] = hv;
                if (ts == 0) h_out[o] = hv;               // one unit writes residual
            }
            __syncthreads();
        }

        // stage this tensor's weights transposed: ws[c*68 + d] = W[d][c]
        for (int i = tid; i < 4096; i += NTHR) {
            int d = i >> 6, c = i & 63;
            ws[c * 68 + d] = wsel[d * 64 + c];
        }
        __syncthreads();

        // 4 nodes x 4 dims per thread
        const int d0  = (tid & 15) * 4;
        const int nl0 = (tid >> 4) * 4;
        float acc[4][4];
        #pragma unroll
        for (int q = 0; q < 4; q++)
            #pragma unroll
            for (int j = 0; j < 4; j++) acc[q][j] = 0.f;

        #pragma unroll 4
        for (int c = 0; c < 64; c++) {
            float4 hv = *(const float4*)&hs[c * 64 + nl0];
            float4 wv = *(const float4*)&ws[c * 68 + d0];
            #pragma unroll
            for (int j = 0; j < 4; j++) {
                float w = (&wv.x)[j];
                acc[0][j] += hv.x * w;
                acc[1][j] += hv.y * w;
                acc[2][j] += hv.z * w;
                acc[3][j] += hv.w * w;
            }
        }
        float4 bias = *(const float4*)&bsel[d0];
        #pragma unroll
        for (int q = 0; q < 4; q++) {
            float4 v;
            v.x = acc[q][0] + bias.x; v.y = acc[q][1] + bias.y;
            v.z = acc[q][2] + bias.z; v.w = acc[q][3] + bias.w;
            *(float4*)&osel[(size_t)(n0 + nl0 + q) * 64 + d0] = v;
        }
        __syncthreads();   // smem reused next unit
    }
}

// ---------------- phase: dense line attention, one wave per line ----------------
// 1728 lines, gl = bid + wv*GRID -> every block gets 1-2 lines (<=7/CU).
// Wave-private LDS (2400 floats = 9.6 KB/wave): th/ph staged in TWO half-d
// rounds of [24][36] each + P[24][28]. g is read directly from L2 (coalesced
// 256B rows, each read exactly once).
__device__ void attn_phase(float* __restrict__ smem,
    const float* __restrict__ theta, const float* __restrict__ phi,
    const float* __restrict__ gv, float* __restrict__ y_part,
    float* __restrict__ l_part, float* __restrict__ gsum)
{
    const int tid = threadIdx.x;
    if (blockIdx.x == 0) {       // zero GN accumulators for the following combine
        for (int i = tid; i < 1024; i += NTHR) gsum[i] = 0.f;
    }
    const int wv = tid >> 6, lane = tid & 63;
    const int gl = blockIdx.x + wv * GRID;
    if (gl >= 1728) return;      // idle waves still reach gbar
    const int axis = gl / 576, L = gl % 576;

    float* th = smem + wv * 2400;   // [24][36] current d-half
    float* ph = th + 864;           // [24][36]
    float* P  = th + 1728;          // [24][28]

    int base, stride;
    if (axis == 0)      { base = L * 24;                    stride = 1;   }
    else if (axis == 1) { base = (L / 24) * 576 + (L % 24); stride = 24;  }
    else                { base = L;                         stride = 576; }
    const bool excl = (axis != 2);

    // S-phase: lane (li,lj) computes rows 3li..+2, cols 3lj..+2; d in 2 halves
    const int r0 = (lane >> 3) * 3, c0 = (lane & 7) * 3;
    float sa[3][3];
    #pragma unroll
    for (int a = 0; a < 3; a++)
        #pragma unroll
        for (int b = 0; b < 3; b++) sa[a][b] = 0.f;

    #pragma unroll
    for (int half = 0; half < 2; half++) {
        const int dbase = half * 32;
        // stage 24 rows x 32 d: 8 lanes per row, 128B contiguous per row
        #pragma unroll
        for (int q = 0; q < 3; q++) {
            int idx = q * 64 + lane;            // 0..191
            int row = idx >> 3, c4 = (idx & 7) * 4;
            size_t g = (size_t)(base + row * stride) * 64 + dbase + c4;
            int la = row * 36 + c4;
            *(float4*)&th[la] = *(const float4*)&theta[g];
            *(float4*)&ph[la] = *(const float4*)&phi[g];
        }
        // wave-private: LDS write->read ordered within wave, no barrier
        #pragma unroll 4
        for (int d4 = 0; d4 < 32; d4 += 4) {
            float4 t[3], p[3];
            #pragma unroll
            for (int a = 0; a < 3; a++) t[a] = *(const float4*)&th[(r0 + a) * 36 + d4];
            #pragma unroll
            for (int b = 0; b < 3; b++) p[b] = *(const float4*)&ph[(c0 + b) * 36 + d4];
            #pragma unroll
            for (int a = 0; a < 3; a++)
                #pragma unroll
                for (int b = 0; b < 3; b++)
                    sa[a][b] += t[a].x * p[b].x + t[a].y * p[b].y +
                                t[a].z * p[b].z + t[a].w * p[b].w;
        }
    }
    #pragma unroll
    for (int a = 0; a < 3; a++)
        #pragma unroll
        for (int b = 0; b < 3; b++) {
            float e = (excl && (r0 + a) == (c0 + b)) ? 0.f : __expf(sa[a][b]);
            P[(r0 + a) * 28 + c0 + b] = e;
        }

    // row sums (lanes 0..23) -> l_part
    if (lane < 24) {
        float s = 0.f;
        #pragma unroll
        for (int c4 = 0; c4 < 24; c4 += 4) {
            float4 pv = *(const float4*)&P[lane * 28 + c4];
            s += pv.x + pv.y + pv.z + pv.w;
        }
        l_part[(size_t)axis * NN + base + lane * stride] = s;
    }

    // Y = P @ g : lane = d, g read directly from L2 (coalesced 256B rows)
    float acc[24];
    #pragma unroll
    for (int r = 0; r < 24; r++) acc[r] = 0.f;
    #pragma unroll
    for (int c4 = 0; c4 < 24; c4 += 4) {
        float g0 = gv[(size_t)(base + (c4 + 0) * stride) * 64 + lane];
        float g1 = gv[(size_t)(base + (c4 + 1) * stride) * 64 + lane];
        float g2 = gv[(size_t)(base + (c4 + 2) * stride) * 64 + lane];
        float g3 = gv[(size_t)(base + (c4 + 3) * stride) * 64 + lane];
        #pragma unroll
        for (int r = 0; r < 24; r++) {
            float4 pv = *(const float4*)&P[r * 28 + c4];  // wave-uniform bcast
            acc[r] += pv.x * g0 + pv.y * g1 + pv.z * g2 + pv.w * g3;
        }
    }
    float* yp = y_part + (size_t)axis * NN * 64;
    #pragma unroll
    for (int r = 0; r < 24; r++)
        yp[(size_t)(base + r * stride) * 64 + lane] = acc[r];
}

// ---------------- phase: combine axes, normalize, project r_w, GN partials ----------------
// 864 units on 1024 blocks: single round.
__device__ void combine_phase(float* __restrict__ smem,
    const float* __restrict__ y_part, const float* __restrict__ l_part,
    const float* __restrict__ r_w, const float* __restrict__ r_b,
    float* __restrict__ cross, float* __restrict__ gsum)
{
    float* ys = smem;               // [16*68]
    float* red_s = smem + 1088;     // [4][64]
    float* red_ss = smem + 1344;    // [4][64]
    const int tid = threadIdx.x;
    const int d = tid & 63, w = tid >> 6;
    const size_t S = (size_t)NN * 64;

    for (int u = blockIdx.x; u < 864; u += GRID) {
        const int n0 = u * 16;
        #pragma unroll
        for (int q = 0; q < 4; q++) {
            int nn = w * 4 + q;
            int n = n0 + nn;
            float lv = l_part[n] + l_part[NN + n] + l_part[2 * NN + n];
            size_t o = (size_t)n * 64 + d;
            float yv = y_part[o] + y_part[S + o] + y_part[2 * S + o];
            ys[nn * 68 + d] = yv / lv;
        }
        __syncthreads();

        const int c = d;
        float rb = r_b[c];
        float acc[4] = {rb, rb, rb, rb};
        for (int dd = 0; dd < 64; dd += 4) {
            float4 r4 = *(const float4*)&r_w[c * 64 + dd];
            #pragma unroll
            for (int q = 0; q < 4; q++) {
                float4 y4 = *(const float4*)&ys[(w * 4 + q) * 68 + dd];
                acc[q] += r4.x * y4.x + r4.y * y4.y + r4.z * y4.z + r4.w * y4.w;
            }
        }
        float s = 0.f, ss = 0.f;
        #pragma unroll
        for (int q = 0; q < 4; q++) {
            int n = n0 + w * 4 + q;
            cross[(size_t)n * 64 + c] = acc[q];
            s += acc[q];
            ss += acc[q] * acc[q];
        }
        red_s[w * 64 + c] = s;
        red_ss[w * 64 + c] = ss;
        __syncthreads();
        if (w == 0) {
            float ts  = red_s[c] + red_s[64 + c] + red_s[128 + c] + red_s[192 + c];
            float tss = red_ss[c] + red_ss[64 + c] + red_ss[128 + c] + red_ss[192 + c];
            ts  += __shfl_xor(ts, 1);  ts  += __shfl_xor(ts, 2);
            tss += __shfl_xor(tss, 1); tss += __shfl_xor(tss, 2);
            if ((c & 3) == 0) {
                atomicAdd(&gsum[(c >> 2) * 16], ts);          // 64B-strided: no contention
                atomicAdd(&gsum[512 + (c >> 2) * 16], tss);
            }
        }
        __syncthreads();   // smem reused next unit
    }
}

// ---------------- phase: h2 = h1 + GN(cross); out = relu(BN(h2)) ----------------
// 864 units x 16 nodes on 1024 blocks: single round, 84% of blocks active.
__device__ void final_phase(float* __restrict__ smem,
    const float* __restrict__ cross, const float* __restrict__ gsum,
    const float* __restrict__ gn_g, const float* __restrict__ gn_b,
    const float* __restrict__ h_in,
    const float* __restrict__ bn_g, const float* __restrict__ bn_b,
    const float* __restrict__ bn_m, const float* __restrict__ bn_v,
    float* __restrict__ out)
{
    float* t = smem;   // [64*17]
    const int tid = threadIdx.x;
    for (int u = blockIdx.x; u < 864; u += GRID) {
        const int n0 = u * 16;
        for (int i = tid; i < 1024; i += NTHR) {
            int nl = i >> 6, c = i & 63;
            t[c * 17 + nl] = cross[(size_t)(n0 + nl) * 64 + c];
        }
        __syncthreads();
        const float inv_cnt = 1.f / 55296.f;
        for (int i = tid; i < 1024; i += NTHR) {
            int c = i >> 4, nl = i & 15;
            int gr = c >> 2;
            float mean = gsum[gr * 16] * inv_cnt;
            float var = gsum[512 + gr * 16] * inv_cnt - mean * mean;
            float v = (t[c * 17 + nl] - mean) * rsqrtf(var + 1e-5f) * gn_g[c] + gn_b[c];
            size_t o = (size_t)c * NN + n0 + nl;
            float h2 = h_in[o] + v;
            float bnv = (h2 - bn_m[c]) * rsqrtf(bn_v[c] + 1e-5f) * bn_g[c] + bn_b[c];
            out[o] = fmaxf(bnv, 0.f);
        }
        __syncthreads();
    }
}

// ---------------- one persistent kernel: 7 launches -> 1 launch + 6 grid barriers ----------------
__global__ __launch_bounds__(NTHR, 4) void fused_all(
    const float* __restrict__ x,
    const float* __restrict__ theta_w, const float* __restrict__ theta_b,
    const float* __restrict__ phi_w, const float* __restrict__ phi_b,
    const float* __restrict__ G_w, const float* __restrict__ G_b,
    const float* __restrict__ r_w, const float* __restrict__ r_b,
    const float* __restrict__ gn_gamma, const float* __restrict__ gn_beta,
    const float* __restrict__ bn_g, const float* __restrict__ bn_b,
    const float* __restrict__ bn_m, const float* __restrict__ bn_v,
    float* __restrict__ h1, float* __restrict__ theta, float* __restrict__ phi,
    float* __restrict__ gv, float* __restrict__ ypart, float* __restrict__ cross,
    float* __restrict__ lpart, float* __restrict__ gsum,
    unsigned* __restrict__ bar, float* __restrict__ out)
{
    // max over phases: attn 4 waves x 2400 = 9600 floats = 38400 B (proj 8448 fl)
    // 4 blocks/CU x 38400 B = 153.6 KB <= 160 KB LDS/CU
    __shared__ float smem[9600];
    unsigned* gen   = bar;        // one line
    unsigned* flags = bar + 32;   // 1024 x 128B-padded per-block flags

    // iter 0
    proj_phase(smem, x, cross, gsum, gn_gamma, gn_beta, h1, 0,
               theta_w, theta_b, phi_w, phi_b, G_w, G_b, theta, phi, gv);
    gbar(flags, gen, 1);
    attn_phase(smem, theta, phi, gv, ypart, lpart, gsum);
    gbar(flags, gen, 2);
    combine_phase(smem, ypart, lpart, r_w, r_b, cross, gsum);
    gbar(flags, gen, 3);
    // iter 1
    proj_phase(smem, x, cross, gsum, gn_gamma, gn_beta, h1, 1,
               theta_w, theta_b, phi_w, phi_b, G_w, G_b, theta, phi, gv);
    gbar(flags, gen, 4);
    attn_phase(smem, theta, phi, gv, ypart, lpart, gsum);
    gbar(flags, gen, 5);
    combine_phase(smem, ypart, lpart, r_w, r_b, cross, gsum);
    gbar(flags, gen, 6);
    // epilogue
    final_phase(smem, cross, gsum, gn_gamma + 64, gn_beta + 64, h1,
                bn_g, bn_b, bn_m, bn_v, out);
}

extern "C" void kernel_launch(void* const* d_in, const int* in_sizes, int n_in,
                              void* d_out, int out_size, void* d_ws, size_t ws_size,
                              hipStream_t stream)
{
    const float* x        = (const float*)d_in[0];
    // d_in[1] = nbr_idx: unused — neighbor structure is separable (3 axis lines)
    const float* phi_w    = (const float*)d_in[2];
    const float* phi_b    = (const float*)d_in[3];
    const float* theta_w  = (const float*)d_in[4];
    const float* theta_b  = (const float*)d_in[5];
    const float* G_w      = (const float*)d_in[6];
    const float* G_b      = (const float*)d_in[7];
    const float* r_w      = (const float*)d_in[8];
    const float* r_b      = (const float*)d_in[9];
    const float* gn_gamma = (const float*)d_in[10];
    const float* gn_beta  = (const float*)d_in[11];
    const float* bn_gamma = (const float*)d_in[12];
    const float* bn_beta  = (const float*)d_in[13];
    const float* bn_mean  = (const float*)d_in[14];
    const float* bn_var   = (const float*)d_in[15];

    float* ws = (float*)d_ws;
    const size_t S = (size_t)NN * 64;
    float* h1    = ws;                   // (64,N) after iter-0 update
    float* theta = ws + S;               // (N,64)
    float* phi   = ws + 2 * S;           // (N,64)
    float* gv    = ws + 3 * S;           // (N,64)
    float* ypart = ws + 4 * S;           // 3 x (N,64) per-axis partials
    float* cross = ws + 7 * S;           // (N,64) — must NOT alias theta
    float* lpart = ws + 8 * S;           // 3 x (N)
    float* gsum  = ws + 8 * S + 3 * NN;  // GN accumulators (1024 floats)
    unsigned* bar = (unsigned*)(ws + 8 * S + 3 * NN + 1024);  // gen + 1024 padded flags

    // barrier state must start at 0 every replay (ws is poisoned between reps);
    // gen (128B) + 1024 flags x 128B. Stream-ordered, graph-capture-safe.
    hipMemsetAsync(bar, 0, 128 + GRID * 128, stream);

    fused_all<<<GRID, NTHR, 0, stream>>>(
        x, theta_w, theta_b, phi_w, phi_b, G_w, G_b, r_w, r_b,
        gn_gamma, gn_beta, bn_gamma, bn_beta, bn_mean, bn_var,
        h1, theta, phi, gv, ypart, cross, lpart, gsum, bar, (float*)d_out);
}

// Round 4
// 218.815 us; speedup vs baseline: 2.5298x; 2.5298x over previous
//
#include <hip/hip_runtime.h>
#include <math.h>

#define NN 13824   // D*H*W
#define LW 24      // line width

// ---------------- fused GN-apply + residual + projection ----------------
// grid = 216 tiles x 3 tensors. Each block computes ONE tensor (theta/phi/g)
// for a 64-node tile: out = hs @ W^T + b, written node-major (N,64).
// mode 0: hs = x tile. mode 1: hs = x + GN(cross); ts==0 block stores h_out.
__global__ __launch_bounds__(256) void apply_proj_kernel(
    const float* __restrict__ x,
    const float* __restrict__ cross, const float* __restrict__ gsum,
    const float* __restrict__ gn_g, const float* __restrict__ gn_b,
    float* __restrict__ h_out, int mode,
    const float* __restrict__ theta_w, const float* __restrict__ theta_b,
    const float* __restrict__ phi_w, const float* __restrict__ phi_b,
    const float* __restrict__ g_w, const float* __restrict__ g_b,
    float* __restrict__ theta, float* __restrict__ phi, float* __restrict__ gv)
{
    __shared__ float hs[64 * 64];   // hs[c*64 + nl]
    __shared__ float ws[64 * 68];   // scratch (cross^T) then weights^T [c*68 + d]

    const int tid = threadIdx.x;
    const int tile = blockIdx.x / 3, ts = blockIdx.x % 3;
    const int n0 = tile * 64;

    const float* wsel = (ts == 0) ? theta_w : (ts == 1) ? phi_w : g_w;
    const float* bsel = (ts == 0) ? theta_b : (ts == 1) ? phi_b : g_b;
    float*       osel = (ts == 0) ? theta   : (ts == 1) ? phi   : gv;

    if (mode == 0) {
        for (int i = tid; i < 4096; i += 256) {
            int c = i >> 6, nl = i & 63;
            hs[c * 64 + nl] = x[(size_t)c * NN + n0 + nl];
        }
    } else {
        for (int i = tid; i < 4096; i += 256) {       // cross^T into scratch
            int nl = i >> 6, c = i & 63;
            ws[c * 68 + nl] = cross[(size_t)(n0 + nl) * 64 + c];
        }
        __syncthreads();
        const float inv_cnt = 1.f / 55296.f;
        for (int i = tid; i < 4096; i += 256) {
            int c = i >> 6, nl = i & 63;
            int gr = c >> 2;
            float mean = gsum[gr * 16] * inv_cnt;
            float var = gsum[512 + gr * 16] * inv_cnt - mean * mean;
            float v = (ws[c * 68 + nl] - mean) * rsqrtf(var + 1e-5f) * gn_g[c] + gn_b[c];
            size_t o = (size_t)c * NN + n0 + nl;
            float hv = x[o] + v;
            hs[c * 64 + nl] = hv;
            if (ts == 0) h_out[o] = hv;               // one block writes residual
        }
        __syncthreads();
    }

    // stage this tensor's weights transposed: ws[c*68 + d] = W[d][c]
    for (int i = tid; i < 4096; i += 256) {
        int d = i >> 6, c = i & 63;
        ws[c * 68 + d] = wsel[d * 64 + c];
    }
    __syncthreads();

    // 4 nodes x 4 dims per thread; lanes consecutive in d for coalesced stores
    const int d0  = (tid & 15) * 4;
    const int nl0 = (tid >> 4) * 4;
    float acc[4][4];
    #pragma unroll
    for (int q = 0; q < 4; q++)
        #pragma unroll
        for (int j = 0; j < 4; j++) acc[q][j] = 0.f;

    #pragma unroll 4
    for (int c = 0; c < 64; c++) {
        float4 hv = *(const float4*)&hs[c * 64 + nl0];
        float4 wv = *(const float4*)&ws[c * 68 + d0];
        #pragma unroll
        for (int j = 0; j < 4; j++) {
            float w = (&wv.x)[j];
            acc[0][j] += hv.x * w;
            acc[1][j] += hv.y * w;
            acc[2][j] += hv.z * w;
            acc[3][j] += hv.w * w;
        }
    }
    float4 bias = *(const float4*)&bsel[d0];
    #pragma unroll
    for (int q = 0; q < 4; q++) {
        float4 v;
        v.x = acc[q][0] + bias.x; v.y = acc[q][1] + bias.y;
        v.z = acc[q][2] + bias.z; v.w = acc[q][3] + bias.w;
        *(float4*)&osel[(size_t)(n0 + nl0 + q) * 64 + d0] = v;
    }
}

// ---------------- dense line attention: one WAVE per line ----------------
// block = 128 threads = 2 waves = 2 lines; wave-private LDS, no barriers.
// grid = 864 covers 1728 lines (3 axes x 576). Per line: S = theta@phi^T
// (3x3 register tiles on an 8x8 lane grid, b128 LDS reads), P = exp(S)
// (no max-subtract: logits O(10), fp32-safe; softmax shift-invariant),
// row sums, Y = P@g with acc[24] in registers and b128 P broadcasts.
// g is NOT staged in LDS (validated R2/R3): each g row is consumed exactly
// once and the direct gv read is a coalesced 256B L2 hit. LDS 44.5->31.5 KB
// per block -> 5 blocks/CU (was 3).
__global__ __launch_bounds__(128) void line_attn_kernel(
    const float* __restrict__ theta,
    const float* __restrict__ phi,
    const float* __restrict__ gv,
    float* __restrict__ y_part,    // 3 buffers of (N,64)
    float* __restrict__ l_part,    // 3 buffers of (N)
    float* __restrict__ gsum)      // zeroed here for combine's atomics
{
    __shared__ float th[2][LW * 68], ph[2][LW * 68];
    __shared__ float P[2][LW * 28];

    const int tid = threadIdx.x;
    const int wv = tid >> 6, lane = tid & 63;
    const int gl = blockIdx.x * 2 + wv;
    const int axis = gl / 576, L = gl % 576;

    if (blockIdx.x == 0) {
        for (int i = tid; i < 1024; i += 128) gsum[i] = 0.f;
    }

    int base, stride;
    if (axis == 0)      { base = L * 24;                    stride = 1;   }
    else if (axis == 1) { base = (L / 24) * 576 + (L % 24); stride = 24;  }
    else                { base = L;                         stride = 576; }
    const bool excl = (axis != 2);

    // stage 24 rows x 64 d of theta/phi (6 float4 per array per lane)
    #pragma unroll
    for (int q = 0; q < 6; q++) {
        int idx = q * 64 + lane;            // 0..383
        int row = idx >> 4, c4 = (idx & 15) * 4;
        size_t g = (size_t)(base + row * stride) * 64 + c4;
        int la = row * 68 + c4;
        *(float4*)&th[wv][la] = *(const float4*)&theta[g];
        *(float4*)&ph[wv][la] = *(const float4*)&phi[g];
    }

    // S-phase: lane (li,lj) computes rows 3li..+2, cols 3lj..+2
    const int r0 = (lane >> 3) * 3, c0 = (lane & 7) * 3;
    float sa[3][3];
    #pragma unroll
    for (int a = 0; a < 3; a++)
        #pragma unroll
        for (int b = 0; b < 3; b++) sa[a][b] = 0.f;

    #pragma unroll 4
    for (int d4 = 0; d4 < 64; d4 += 4) {
        float4 t[3], p[3];
        #pragma unroll
        for (int a = 0; a < 3; a++) t[a] = *(const float4*)&th[wv][(r0 + a) * 68 + d4];
        #pragma unroll
        for (int b = 0; b < 3; b++) p[b] = *(const float4*)&ph[wv][(c0 + b) * 68 + d4];
        #pragma unroll
        for (int a = 0; a < 3; a++)
            #pragma unroll
            for (int b = 0; b < 3; b++)
                sa[a][b] += t[a].x * p[b].x + t[a].y * p[b].y +
                            t[a].z * p[b].z + t[a].w * p[b].w;
    }
    #pragma unroll
    for (int a = 0; a < 3; a++)
        #pragma unroll
        for (int b = 0; b < 3; b++) {
            float e = (excl && (r0 + a) == (c0 + b)) ? 0.f : __expf(sa[a][b]);
            P[wv][(r0 + a) * 28 + c0 + b] = e;
        }

    // row sums (lanes 0..23) -> l_part
    if (lane < 24) {
        float s = 0.f;
        #pragma unroll
        for (int c4 = 0; c4 < 24; c4 += 4) {
            float4 pv = *(const float4*)&P[wv][lane * 28 + c4];
            s += pv.x + pv.y + pv.z + pv.w;
        }
        l_part[(size_t)axis * NN + base + lane * stride] = s;
    }

    // Y = P @ g : lane = d, 24 row accumulators; g read direct (coalesced 256B)
    float acc[24];
    #pragma unroll
    for (int r = 0; r < 24; r++) acc[r] = 0.f;
    #pragma unroll
    for (int c4 = 0; c4 < 24; c4 += 4) {
        float g0 = gv[(size_t)(base + (c4 + 0) * stride) * 64 + lane];
        float g1 = gv[(size_t)(base + (c4 + 1) * stride) * 64 + lane];
        float g2 = gv[(size_t)(base + (c4 + 2) * stride) * 64 + lane];
        float g3 = gv[(size_t)(base + (c4 + 3) * stride) * 64 + lane];
        #pragma unroll
        for (int r = 0; r < 24; r++) {
            float4 pv = *(const float4*)&P[wv][r * 28 + c4];  // wave-uniform bcast
            acc[r] += pv.x * g0 + pv.y * g1 + pv.z * g2 + pv.w * g3;
        }
    }
    float* yp = y_part + (size_t)axis * NN * 64;
    #pragma unroll
    for (int r = 0; r < 24; r++)
        yp[(size_t)(base + r * stride) * 64 + lane] = acc[r];
}

// ---------------- combine: merge axes, normalize, project r_w, GN partials ----------------
__global__ __launch_bounds__(256) void combine_kernel(
    const float* __restrict__ y_part, const float* __restrict__ l_part,
    const float* __restrict__ r_w, const float* __restrict__ r_b,
    float* __restrict__ cross, float* __restrict__ gsum)
{
    __shared__ float ys[16 * 68];
    __shared__ float red_s[4][64], red_ss[4][64];

    const int tid = threadIdx.x;
    const int d = tid & 63, w = tid >> 6;
    const int n0 = blockIdx.x * 16;
    const size_t S = (size_t)NN * 64;

    #pragma unroll
    for (int q = 0; q < 4; q++) {
        int nn = w * 4 + q;
        int n = n0 + nn;
        float lv = l_part[n] + l_part[NN + n] + l_part[2 * NN + n];
        size_t o = (size_t)n * 64 + d;
        float yv = y_part[o] + y_part[S + o] + y_part[2 * S + o];
        ys[nn * 68 + d] = yv / lv;
    }
    __syncthreads();

    const int c = d;
    float rb = r_b[c];
    float acc[4] = {rb, rb, rb, rb};
    for (int dd = 0; dd < 64; dd += 4) {
        float4 r4 = *(const float4*)&r_w[c * 64 + dd];
        #pragma unroll
        for (int q = 0; q < 4; q++) {
            float4 y4 = *(const float4*)&ys[(w * 4 + q) * 68 + dd];
            acc[q] += r4.x * y4.x + r4.y * y4.y + r4.z * y4.z + r4.w * y4.w;
        }
    }
    float s = 0.f, ss = 0.f;
    #pragma unroll
    for (int q = 0; q < 4; q++) {
        int n = n0 + w * 4 + q;
        cross[(size_t)n * 64 + c] = acc[q];
        s += acc[q];
        ss += acc[q] * acc[q];
    }
    red_s[w][c] = s;
    red_ss[w][c] = ss;
    __syncthreads();
    if (w == 0) {
        float ts  = red_s[0][c] + red_s[1][c] + red_s[2][c] + red_s[3][c];
        float tss = red_ss[0][c] + red_ss[1][c] + red_ss[2][c] + red_ss[3][c];
        ts  += __shfl_xor(ts, 1);  ts  += __shfl_xor(ts, 2);
        tss += __shfl_xor(tss, 1); tss += __shfl_xor(tss, 2);
        if ((c & 3) == 0) {
            atomicAdd(&gsum[(c >> 2) * 16], ts);          // 64B-strided: no contention
            atomicAdd(&gsum[512 + (c >> 2) * 16], tss);
        }
    }
}

// ---------------- final: h2 = h1 + GN(cross); out = relu(BN(h2)) ----------------
__global__ __launch_bounds__(256) void final_kernel(
    const float* __restrict__ cross,
    const float* __restrict__ gsum,
    const float* __restrict__ gn_g, const float* __restrict__ gn_b,
    const float* __restrict__ h_in,
    const float* __restrict__ bn_g, const float* __restrict__ bn_b,
    const float* __restrict__ bn_m, const float* __restrict__ bn_v,
    float* __restrict__ out)
{
    __shared__ float t[64 * 65];
    const int tid = threadIdx.x;
    const int n0 = blockIdx.x * 64;
    for (int i = tid; i < 4096; i += 256) {
        int nl = i >> 6, c = i & 63;
        t[c * 65 + nl] = cross[(size_t)(n0 + nl) * 64 + c];
    }
    __syncthreads();
    const float inv_cnt = 1.f / 55296.f;
    for (int i = tid; i < 4096; i += 256) {
        int c = i >> 6, nl = i & 63;
        int gr = c >> 2;
        float mean = gsum[gr * 16] * inv_cnt;
        float var = gsum[512 + gr * 16] * inv_cnt - mean * mean;
        float v = (t[c * 65 + nl] - mean) * rsqrtf(var + 1e-5f) * gn_g[c] + gn_b[c];
        size_t o = (size_t)c * NN + n0 + nl;
        float h2 = h_in[o] + v;
        float bnv = (h2 - bn_m[c]) * rsqrtf(bn_v[c] + 1e-5f) * bn_g[c] + bn_b[c];
        out[o] = fmaxf(bnv, 0.f);
    }
}

extern "C" void kernel_launch(void* const* d_in, const int* in_sizes, int n_in,
                              void* d_out, int out_size, void* d_ws, size_t ws_size,
                              hipStream_t stream)
{
    const float* x        = (const float*)d_in[0];
    // d_in[1] = nbr_idx: unused — neighbor structure is separable (3 axis lines)
    const float* phi_w    = (const float*)d_in[2];
    const float* phi_b    = (const float*)d_in[3];
    const float* theta_w  = (const float*)d_in[4];
    const float* theta_b  = (const float*)d_in[5];
    const float* G_w      = (const float*)d_in[6];
    const float* G_b      = (const float*)d_in[7];
    const float* r_w      = (const float*)d_in[8];
    const float* r_b      = (const float*)d_in[9];
    const float* gn_gamma = (const float*)d_in[10];
    const float* gn_beta  = (const float*)d_in[11];
    const float* bn_gamma = (const float*)d_in[12];
    const float* bn_beta  = (const float*)d_in[13];
    const float* bn_mean  = (const float*)d_in[14];
    const float* bn_var   = (const float*)d_in[15];

    float* ws = (float*)d_ws;
    const size_t S = (size_t)NN * 64;
    float* h1    = ws;             // (64,N) after iter-0 update
    float* theta = ws + S;         // (N,64)
    float* phi   = ws + 2 * S;     // (N,64)
    float* gv    = ws + 3 * S;     // (N,64)
    float* ypart = ws + 4 * S;     // 3 x (N,64) per-axis partials
    float* cross = ws + 7 * S;     // (N,64) — must NOT alias theta (race in apply_proj)
    float* lpart = ws + 8 * S;     // 3 x (N)
    float* gsum  = ws + 8 * S + 3 * NN;  // GN accumulators (1024 floats)

    // iter 0
    apply_proj_kernel<<<648, 256, 0, stream>>>(x, cross, gsum, gn_gamma, gn_beta,
                                               h1, 0,
                                               theta_w, theta_b, phi_w, phi_b,
                                               G_w, G_b, theta, phi, gv);
    line_attn_kernel<<<864, 128, 0, stream>>>(theta, phi, gv, ypart, lpart, gsum);
    combine_kernel<<<864, 256, 0, stream>>>(ypart, lpart, r_w, r_b, cross, gsum);
    // iter 1
    apply_proj_kernel<<<648, 256, 0, stream>>>(x, cross, gsum, gn_gamma, gn_beta,
                                               h1, 1,
                                               theta_w, theta_b, phi_w, phi_b,
                                               G_w, G_b, theta, phi, gv);
    line_attn_kernel<<<864, 128, 0, stream>>>(theta, phi, gv, ypart, lpart, gsum);
    combine_kernel<<<864, 256, 0, stream>>>(ypart, lpart, r_w, r_b, cross, gsum);
    // epilogue
    final_kernel<<<216, 256, 0, stream>>>(cross, gsum, gn_gamma + 64, gn_beta + 64,
                                          h1, bn_gamma, bn_beta, bn_mean, bn_var,
                                          (float*)d_out);
}